// Round 1
// baseline (115.185 us; speedup 1.0000x reference)
//
#include <hip/hip_runtime.h>

#define NV 16
#define NC 16
#define NH 1024
#define NW 1024
#define NRM 8
#define NRD 4
#define ROWS 2

struct cfloat { float x, y; };

// atan2 via degree-11 minimax poly on [0,1]; max err ~1e-6 rad (tolerance is ~2e-2 relative)
__device__ __forceinline__ float fast_atan2f(float y, float x) {
    float ax = fabsf(x), ay = fabsf(y);
    float mx = fmaxf(ax, ay), mn = fminf(ax, ay);
    float a = __fdividef(mn, mx);
    float s = a * a;
    float p =              -0.01172120f;
    p = fmaf(p, s,  0.05265332f);
    p = fmaf(p, s, -0.11643287f);
    p = fmaf(p, s,  0.19354346f);
    p = fmaf(p, s, -0.33262347f);
    p = fmaf(p, s,  0.99997726f);
    p = p * a;
    float t = (ay > ax) ? (1.57079632679f - p) : p;
    t = (x < 0.0f) ? (3.14159265359f - t) : t;
    return (y < 0.0f) ? -t : t;
}

// z^w = exp(w * log z), complex
__device__ __forceinline__ cfloat cpow_(float zr, float zi, float wr, float wi) {
    float L  = 0.5f * __logf(fmaf(zr, zr, zi * zi));
    float th = fast_atan2f(zi, zr);
    float er = fmaf(wr, L,  -wi * th);   // wr*L - wi*th
    float ei = fmaf(wr, th,  wi * L);    // wr*th + wi*L
    float m  = __expf(er);
    float sv, cv;
    __sincosf(ei, &sv, &cv);
    cfloat r; r.x = m * cv; r.y = m * sv; return r;
}

__global__ __launch_bounds__(256, 2)
void fused_kernel(const float* __restrict__ base, const float* __restrict__ mod_u,
                  const float* __restrict__ mod_v, const float* __restrict__ del_u,
                  const float* __restrict__ del_v, const float* __restrict__ exp_base,
                  const float* __restrict__ exp_mod, const float* __restrict__ exp_del,
                  const float* __restrict__ bias_, const float* __restrict__ scale_,
                  const float* __restrict__ coef, float* __restrict__ out)
{
    // block-uniform h (4 blocks of 256 threads span one 1024-wide row-pair chunk)
    const int wchunk = blockIdx.x & 3;
    const int hp     = blockIdx.x >> 2;          // row-pair index [0, 512)
    const int w      = (wchunk << 8) | threadIdx.x;
    const int h0     = hp * ROWS;

    const float ebr = exp_base[0], ebi = exp_base[1];

    // base power, per row
    cfloat pb[ROWS];
    #pragma unroll
    for (int rr = 0; rr < ROWS; ++rr) {
        const float2 b = reinterpret_cast<const float2*>(base)[(h0 + rr) * NW + w];
        pb[rr] = cpow_(b.x, b.y, ebr, ebi);
    }

    float accr[ROWS][NV], acci[ROWS][NV];
    #pragma unroll
    for (int rr = 0; rr < ROWS; ++rr) {
        #pragma unroll
        for (int v = 0; v < NV; ++v) { accr[rr][v] = 0.0f; acci[rr][v] = 0.0f; }
    }

    #pragma unroll 1   // keep rolled: big body, 16 iterations
    for (int c = 0; c < NC; ++c) {
        // w-dependent low-rank factors (shared across both rows)
        float2 mv[NRM];
        #pragma unroll
        for (int r = 0; r < NRM; ++r)
            mv[r] = reinterpret_cast<const float2*>(mod_v)[(c * NRM + r) * NW + w];
        float2 dv[NRD];
        #pragma unroll
        for (int r = 0; r < NRD; ++r)
            dv[r] = reinterpret_cast<const float2*>(del_v)[(c * NRD + r) * NW + w];

        // block-uniform per-c params (scalar loads)
        const float emr = exp_mod[2*c], emi = exp_mod[2*c+1];
        const float edr = exp_del[2*c], edi = exp_del[2*c+1];
        const float sr  = scale_[2*c],  si  = scale_[2*c+1];
        const float br  = bias_[2*c],   bi  = bias_[2*c+1];

        #pragma unroll
        for (int rr = 0; rr < ROWS; ++rr) {
            const int h = h0 + rr;
            // mod[c,h,w] = sum_r mod_u[c,h,r] * mod_v[c,r,w]   (complex)
            float mr = 0.0f, mi_ = 0.0f;
            #pragma unroll
            for (int r = 0; r < NRM; ++r) {
                const float2 u = reinterpret_cast<const float2*>(mod_u)[(c * NH + h) * NRM + r];
                mr  = fmaf(u.x, mv[r].x, fmaf(-u.y, mv[r].y, mr));
                mi_ = fmaf(u.x, mv[r].y, fmaf( u.y, mv[r].x, mi_));
            }
            float dr = 0.0f, di = 0.0f;
            #pragma unroll
            for (int r = 0; r < NRD; ++r) {
                const float2 u = reinterpret_cast<const float2*>(del_u)[(c * NH + h) * NRD + r];
                dr = fmaf(u.x, dv[r].x, fmaf(-u.y, dv[r].y, dr));
                di = fmaf(u.x, dv[r].y, fmaf( u.y, dv[r].x, di));
            }

            const cfloat pm = cpow_(mr, mi_, emr, emi);
            const cfloat pd = cpow_(dr, di,  edr, edi);

            // t = pb*pm + pd
            const float tr = fmaf(pb[rr].x, pm.x, fmaf(-pb[rr].y, pm.y, pd.x));
            const float ti = fmaf(pb[rr].x, pm.y, fmaf( pb[rr].y, pm.x, pd.y));
            // comp = scale*t + bias
            const float cr_ = fmaf(sr, tr, fmaf(-si, ti, br));
            const float ci_ = fmaf(sr, ti, fmaf( si, tr, bi));

            // out[v] += coef[v,c] * comp   (coef loads are block-uniform)
            #pragma unroll
            for (int v = 0; v < NV; ++v) {
                const float kr = coef[(v * NC + c) * 2];
                const float ki = coef[(v * NC + c) * 2 + 1];
                accr[rr][v] = fmaf(kr, cr_, fmaf(-ki, ci_, accr[rr][v]));
                acci[rr][v] = fmaf(kr, ci_, fmaf( ki, cr_, acci[rr][v]));
            }
        }
    }

    #pragma unroll
    for (int rr = 0; rr < ROWS; ++rr) {
        const int idx = (h0 + rr) * NW + w;
        #pragma unroll
        for (int v = 0; v < NV; ++v) {
            reinterpret_cast<float2*>(out)[v * (NH * NW) + idx] =
                make_float2(accr[rr][v], acci[rr][v]);
        }
    }
}

extern "C" void kernel_launch(void* const* d_in, const int* in_sizes, int n_in,
                              void* d_out, int out_size, void* d_ws, size_t ws_size,
                              hipStream_t stream) {
    const float* base     = (const float*)d_in[0];
    const float* mod_u    = (const float*)d_in[1];
    const float* mod_v    = (const float*)d_in[2];
    const float* del_u    = (const float*)d_in[3];
    const float* del_v    = (const float*)d_in[4];
    const float* exp_base = (const float*)d_in[5];
    const float* exp_mod  = (const float*)d_in[6];
    const float* exp_del  = (const float*)d_in[7];
    const float* bias_    = (const float*)d_in[8];
    const float* scale_   = (const float*)d_in[9];
    const float* coef     = (const float*)d_in[10];
    float* outp = (float*)d_out;

    const int blocks = (NH / ROWS) * (NW / 256);   // 512 * 4 = 2048
    fused_kernel<<<blocks, 256, 0, stream>>>(base, mod_u, mod_v, del_u, del_v,
                                             exp_base, exp_mod, exp_del,
                                             bias_, scale_, coef, outp);
}

// Round 3
// 114.781 us; speedup vs baseline: 1.0035x; 1.0035x over previous
//
#include <hip/hip_runtime.h>
#include <stdint.h>

#define NV 16
#define NC 16
#define NH 1024
#define NW 1024
#define NRM 8
#define NRD 4

typedef __attribute__((ext_vector_type(4))) _Float16 f16x4;
typedef __attribute__((ext_vector_type(2))) __fp16 fp16x2_raw;
typedef __attribute__((ext_vector_type(4))) float f32x4;

#define MFMA16(a, b, c) __builtin_amdgcn_mfma_f32_16x16x16f16((a), (b), (c), 0, 0, 0)

struct cfloat { float x, y; };

__device__ __forceinline__ uint32_t pkh(float a, float b) {
    fp16x2_raw h = __builtin_amdgcn_cvt_pkrtz(a, b);   // lo = a, hi = b, RTZ
    return __builtin_bit_cast(uint32_t, h);
}

__device__ __forceinline__ f16x4 mk4(uint32_t lo, uint32_t hi) {
    union { uint32_t u[2]; f16x4 v; } t;
    t.u[0] = lo; t.u[1] = hi;
    return t.v;
}

// atan2 via degree-11 minimax poly on [0,1]; max err ~1e-6 rad
__device__ __forceinline__ float fast_atan2f(float y, float x) {
    float ax = fabsf(x), ay = fabsf(y);
    float mx = fmaxf(ax, ay), mn = fminf(ax, ay);
    float a = __fdividef(mn, mx);
    float s = a * a;
    float p =              -0.01172120f;
    p = fmaf(p, s,  0.05265332f);
    p = fmaf(p, s, -0.11643287f);
    p = fmaf(p, s,  0.19354346f);
    p = fmaf(p, s, -0.33262347f);
    p = fmaf(p, s,  0.99997726f);
    p = p * a;
    float t = (ay > ax) ? (1.57079632679f - p) : p;
    t = (x < 0.0f) ? (3.14159265359f - t) : t;
    return (y < 0.0f) ? -t : t;
}

// z^w = exp(w * log z), complex
__device__ __forceinline__ cfloat cpow_(float zr, float zi, float wr, float wi) {
    float L  = 0.5f * __logf(fmaf(zr, zr, zi * zi));
    float th = fast_atan2f(zi, zr);
    float er = fmaf(wr, L,  -wi * th);
    float ei = fmaf(wr, th,  wi * L);
    float m  = __expf(er);
    float sv, cv;
    __sincosf(ei, &sv, &cv);
    cfloat r; r.x = m * cv; r.y = m * sv; return r;
}

#define CMAC(AR, AI, BR, BI) do { \
    tr_ = fmaf((AR), (BR), fmaf(-(AI), (BI), tr_)); \
    ti_ = fmaf((AR), (BI), fmaf( (AI), (BR), ti_)); } while (0)

__global__ __launch_bounds__(256)
void fused_kernel(const float* __restrict__ base, const float* __restrict__ mod_u,
                  const float* __restrict__ mod_v, const float* __restrict__ del_u,
                  const float* __restrict__ del_v, const float* __restrict__ exp_base,
                  const float* __restrict__ exp_mod, const float* __restrict__ exp_del,
                  const float* __restrict__ bias_, const float* __restrict__ scale_,
                  const float* __restrict__ coef, float* __restrict__ out)
{
    // wave-private staging: [2 rows][4 waves][64 pixels][16 c] u32 (f16 r,i packed)
    __shared__ uint32_t lds[8192];   // 32 KB

    const int tid    = threadIdx.x;
    const int lane   = tid & 63;
    const int wv     = tid >> 6;
    const int wchunk = (int)(blockIdx.x & 3);
    const int hp     = (int)(blockIdx.x >> 2);
    const int w      = (wchunk << 8) | tid;
    const int h0     = hp * 2;
    const int wbase  = (wchunk << 8) | (wv << 6);

    // ---------- per-thread A-fragments + bias-const accumulator seed ----------
    const int vv = lane & 15;          // M index (v)
    const int c0 = (lane >> 4) << 2;   // K block (c)

    const float4 cfa = *reinterpret_cast<const float4*>(coef   + (vv * NC + c0) * 2);
    const float4 cfb = *reinterpret_cast<const float4*>(coef   + (vv * NC + c0) * 2 + 4);
    const float4 sca = *reinterpret_cast<const float4*>(scale_ + c0 * 2);
    const float4 scb = *reinterpret_cast<const float4*>(scale_ + c0 * 2 + 4);
    const float4 bia = *reinterpret_cast<const float4*>(bias_  + c0 * 2);
    const float4 bib = *reinterpret_cast<const float4*>(bias_  + c0 * 2 + 4);

    // coef2 = coef * scale (complex, fp32 then f16)
    float c2r0 = cfa.x*sca.x - cfa.y*sca.y, c2i0 = cfa.x*sca.y + cfa.y*sca.x;
    float c2r1 = cfa.z*sca.z - cfa.w*sca.w, c2i1 = cfa.z*sca.w + cfa.w*sca.z;
    float c2r2 = cfb.x*scb.x - cfb.y*scb.y, c2i2 = cfb.x*scb.y + cfb.y*scb.x;
    float c2r3 = cfb.z*scb.z - cfb.w*scb.w, c2i3 = cfb.z*scb.w + cfb.w*scb.z;

    const f16x4 Ar = mk4(pkh(c2r0, c2r1), pkh(c2r2, c2r3));
    const f16x4 Ai = mk4(pkh(c2i0, c2i1), pkh(c2i2, c2i3));
    const f16x4 An = mk4(pkh(-c2i0, -c2i1), pkh(-c2i2, -c2i3));

    // raw coef frags (for bias term: out += sum_c coef[v,c]*bias[c])
    const f16x4 Kr = mk4(pkh(cfa.x, cfa.z), pkh(cfb.x, cfb.z));
    const f16x4 Ki = mk4(pkh(cfa.y, cfa.w), pkh(cfb.y, cfb.w));
    const f16x4 Kn = mk4(pkh(-cfa.y, -cfa.w), pkh(-cfb.y, -cfb.w));

    // B-frags of bias (col-independent => D replicated across cols)
    const f16x4 Bbr = mk4(pkh(bia.x, bia.z), pkh(bib.x, bib.z));
    const f16x4 Bbi = mk4(pkh(bia.y, bia.w), pkh(bib.y, bib.w));

    const f32x4 zero4 = {0.f, 0.f, 0.f, 0.f};
    const f32x4 cr4 = MFMA16(Kr, Bbr, MFMA16(Kn, Bbi, zero4));  // Re(sum coef*bias)
    const f32x4 ci4 = MFMA16(Ki, Bbr, MFMA16(Kr, Bbi, zero4));  // Im(sum coef*bias)

    // ---------- base power, per row ----------
    const float ebr = exp_base[0], ebi = exp_base[1];
    const float2 b0 = reinterpret_cast<const float2*>(base)[(h0    ) * NW + w];
    const float2 b1 = reinterpret_cast<const float2*>(base)[(h0 + 1) * NW + w];
    const cfloat pb0 = cpow_(b0.x, b0.y, ebr, ebi);
    const cfloat pb1 = cpow_(b1.x, b1.y, ebr, ebi);

    uint32_t* wlds0 = lds + (wv << 10);          // row 0 region (4 KB/wave)
    uint32_t* wlds1 = lds + 4096 + (wv << 10);   // row 1 region
    const int swz_w = (lane >> 1) & 3;

    // ---------- main loop over c: compute P[c] = pb*pm + pd, stage to LDS ----------
    #pragma unroll 1
    for (int a = 0; a < 4; ++a) {
        uint32_t p0x, p0y, p0z, p0w, p1x, p1y, p1z, p1w;
        #pragma unroll
        for (int j = 0; j < 4; ++j) {
            const int c = (a << 2) | j;
            // w-dependent low-rank factors (shared across both rows)
            float2 mv0 = reinterpret_cast<const float2*>(mod_v)[(c * NRM + 0) * NW + w];
            float2 mv1 = reinterpret_cast<const float2*>(mod_v)[(c * NRM + 1) * NW + w];
            float2 mv2 = reinterpret_cast<const float2*>(mod_v)[(c * NRM + 2) * NW + w];
            float2 mv3 = reinterpret_cast<const float2*>(mod_v)[(c * NRM + 3) * NW + w];
            float2 mv4 = reinterpret_cast<const float2*>(mod_v)[(c * NRM + 4) * NW + w];
            float2 mv5 = reinterpret_cast<const float2*>(mod_v)[(c * NRM + 5) * NW + w];
            float2 mv6 = reinterpret_cast<const float2*>(mod_v)[(c * NRM + 6) * NW + w];
            float2 mv7 = reinterpret_cast<const float2*>(mod_v)[(c * NRM + 7) * NW + w];
            float2 dv0 = reinterpret_cast<const float2*>(del_v)[(c * NRD + 0) * NW + w];
            float2 dv1 = reinterpret_cast<const float2*>(del_v)[(c * NRD + 1) * NW + w];
            float2 dv2 = reinterpret_cast<const float2*>(del_v)[(c * NRD + 2) * NW + w];
            float2 dv3 = reinterpret_cast<const float2*>(del_v)[(c * NRD + 3) * NW + w];

            const float emr = exp_mod[2*c], emi = exp_mod[2*c+1];
            const float edr = exp_del[2*c], edi = exp_del[2*c+1];

            #pragma unroll
            for (int rr = 0; rr < 2; ++rr) {
                const int h = h0 + rr;
                const float4* mu = reinterpret_cast<const float4*>(mod_u + (c * NH + h) * NRM * 2);
                const float4 ua = mu[0], ub = mu[1], uc_ = mu[2], ud = mu[3];
                const float4* du = reinterpret_cast<const float4*>(del_u + (c * NH + h) * NRD * 2);
                const float4 da = du[0], db = du[1];

                float tr_ = 0.f, ti_ = 0.f;
                CMAC(ua.x,  ua.y,  mv0.x, mv0.y);
                CMAC(ua.z,  ua.w,  mv1.x, mv1.y);
                CMAC(ub.x,  ub.y,  mv2.x, mv2.y);
                CMAC(ub.z,  ub.w,  mv3.x, mv3.y);
                CMAC(uc_.x, uc_.y, mv4.x, mv4.y);
                CMAC(uc_.z, uc_.w, mv5.x, mv5.y);
                CMAC(ud.x,  ud.y,  mv6.x, mv6.y);
                CMAC(ud.z,  ud.w,  mv7.x, mv7.y);
                const float mr = tr_, mi_ = ti_;

                tr_ = 0.f; ti_ = 0.f;
                CMAC(da.x, da.y, dv0.x, dv0.y);
                CMAC(da.z, da.w, dv1.x, dv1.y);
                CMAC(db.x, db.y, dv2.x, dv2.y);
                CMAC(db.z, db.w, dv3.x, dv3.y);
                const float dr = tr_, di = ti_;

                const cfloat pm = cpow_(mr, mi_, emr, emi);
                const cfloat pd = cpow_(dr, di,  edr, edi);

                const float pbr = rr ? pb1.x : pb0.x;
                const float pbi = rr ? pb1.y : pb0.y;
                // P = pb*pm + pd
                const float Pr = fmaf(pbr, pm.x, fmaf(-pbi, pm.y, pd.x));
                const float Pi = fmaf(pbr, pm.y, fmaf( pbi, pm.x, pd.y));
                const uint32_t pk = pkh(Pr, Pi);
                if (rr == 0) { if (j==0) p0x=pk; else if (j==1) p0y=pk; else if (j==2) p0z=pk; else p0w=pk; }
                else         { if (j==0) p1x=pk; else if (j==1) p1y=pk; else if (j==2) p1z=pk; else p1w=pk; }
            }
        }
        const int s = (a ^ swz_w) << 2;   // swizzled 16B slot
        *reinterpret_cast<uint4*>(wlds0 + (lane << 4) + s) = make_uint4(p0x, p0y, p0z, p0w);
        *reinterpret_cast<uint4*>(wlds1 + (lane << 4) + s) = make_uint4(p1x, p1y, p1z, p1w);
    }

    // ---------- MFMA einsum: out[v,pix] = sum_c coef2[v,c] * P[c,pix] + const ----------
    const int ar  = lane >> 4;    // k-block this lane reads (B-frag) / v-block it owns (D)
    const int col = lane & 15;
    float2* outp = reinterpret_cast<float2*>(out);

    #pragma unroll
    for (int rr = 0; rr < 2; ++rr) {
        const uint32_t* reg = rr ? wlds1 : wlds0;
        const int h = h0 + rr;
        #pragma unroll
        for (int g = 0; g < 4; ++g) {
            const int p = (g << 4) | col;
            const int s = (ar ^ ((p >> 1) & 3)) << 2;
            const uint4 q = *reinterpret_cast<const uint4*>(reg + (p << 4) + s);
            // unpack: B-frag f16x4 of P_r and P_i for c = 4*ar..4*ar+3
            const f16x4 Brf = mk4(__builtin_amdgcn_perm(q.y, q.x, 0x05040100u),
                                  __builtin_amdgcn_perm(q.w, q.z, 0x05040100u));
            const f16x4 Bif = mk4(__builtin_amdgcn_perm(q.y, q.x, 0x07060302u),
                                  __builtin_amdgcn_perm(q.w, q.z, 0x07060302u));
            const f32x4 Dr = MFMA16(Ar, Brf, MFMA16(An, Bif, cr4));
            const f32x4 Di = MFMA16(Ai, Brf, MFMA16(Ar, Bif, ci4));
            const int wg = wbase + (g << 4) + col;
            const int base_idx = h * NW + wg;
            #pragma unroll
            for (int j = 0; j < 4; ++j) {
                const int v = (ar << 2) + j;
                outp[v * (NH * NW) + base_idx] = make_float2(Dr[j], Di[j]);
            }
        }
    }
}

extern "C" void kernel_launch(void* const* d_in, const int* in_sizes, int n_in,
                              void* d_out, int out_size, void* d_ws, size_t ws_size,
                              hipStream_t stream) {
    const float* base     = (const float*)d_in[0];
    const float* mod_u    = (const float*)d_in[1];
    const float* mod_v    = (const float*)d_in[2];
    const float* del_u    = (const float*)d_in[3];
    const float* del_v    = (const float*)d_in[4];
    const float* exp_base = (const float*)d_in[5];
    const float* exp_mod  = (const float*)d_in[6];
    const float* exp_del  = (const float*)d_in[7];
    const float* bias_    = (const float*)d_in[8];
    const float* scale_   = (const float*)d_in[9];
    const float* coef     = (const float*)d_in[10];
    float* outp = (float*)d_out;

    const int blocks = (NH / 2) * (NW / 256);   // 512 * 4 = 2048
    fused_kernel<<<blocks, 256, 0, stream>>>(base, mod_u, mod_v, del_u, del_v,
                                             exp_base, exp_mod, exp_del,
                                             bias_, scale_, coef, outp);
}

// Round 4
// 103.897 us; speedup vs baseline: 1.1086x; 1.1048x over previous
//
#include <hip/hip_runtime.h>
#include <stdint.h>

#define NV 16
#define NC 16
#define NH 1024
#define NW 1024
#define NRM 8
#define NRD 4

typedef __attribute__((ext_vector_type(4))) _Float16 f16x4;
typedef __attribute__((ext_vector_type(2))) __fp16 fp16x2_raw;
typedef __attribute__((ext_vector_type(4))) float f32x4;

#define MFMA16(a, b, c) __builtin_amdgcn_mfma_f32_16x16x16f16((a), (b), (c), 0, 0, 0)

struct cfloat { float x, y; };

__device__ __forceinline__ uint32_t pkh(float a, float b) {
    fp16x2_raw h = __builtin_amdgcn_cvt_pkrtz(a, b);   // lo = a, hi = b, RTZ
    return __builtin_bit_cast(uint32_t, h);
}

__device__ __forceinline__ f16x4 mk4(uint32_t lo, uint32_t hi) {
    union { uint32_t u[2]; f16x4 v; } t;
    t.u[0] = lo; t.u[1] = hi;
    return t.v;
}

// atan2 via degree-11 minimax poly on [0,1]; max err ~1e-6 rad
__device__ __forceinline__ float fast_atan2f(float y, float x) {
    float ax = fabsf(x), ay = fabsf(y);
    float mx = fmaxf(ax, ay), mn = fminf(ax, ay);
    float a = __fdividef(mn, mx);
    float s = a * a;
    float p =              -0.01172120f;
    p = fmaf(p, s,  0.05265332f);
    p = fmaf(p, s, -0.11643287f);
    p = fmaf(p, s,  0.19354346f);
    p = fmaf(p, s, -0.33262347f);
    p = fmaf(p, s,  0.99997726f);
    p = p * a;
    float t = (ay > ax) ? (1.57079632679f - p) : p;
    t = (x < 0.0f) ? (3.14159265359f - t) : t;
    return (y < 0.0f) ? -t : t;
}

// z^w = exp(w * log z), complex
__device__ __forceinline__ cfloat cpow_(float zr, float zi, float wr, float wi) {
    float L  = 0.5f * __logf(fmaf(zr, zr, zi * zi));
    float th = fast_atan2f(zi, zr);
    float er = fmaf(wr, L,  -wi * th);
    float ei = fmaf(wr, th,  wi * L);
    float m  = __expf(er);
    float sv, cv;
    __sincosf(ei, &sv, &cv);
    cfloat r; r.x = m * cv; r.y = m * sv; return r;
}

#define CMAC(AR, AI, BR, BI) do { \
    tr_ = fmaf((AR), (BR), fmaf(-(AI), (BI), tr_)); \
    ti_ = fmaf((AR), (BI), fmaf( (AI), (BR), ti_)); } while (0)

// -------- pre-pass: transpose mod_v/del_v to [c][w][r] (contiguous r) --------
__global__ __launch_bounds__(256)
void transpose_v(const float* __restrict__ mod_v, const float* __restrict__ del_v,
                 float* __restrict__ mvT, float* __restrict__ dvT)
{
    const int idx = blockIdx.x * 256 + threadIdx.x;   // c*NW + w
    const int c = idx >> 10, w = idx & 1023;
    float2* mt = reinterpret_cast<float2*>(mvT) + idx * NRM;
    const float2* ms = reinterpret_cast<const float2*>(mod_v) + c * NRM * NW + w;
    #pragma unroll
    for (int r = 0; r < NRM; ++r) mt[r] = ms[r * NW];
    float2* dt = reinterpret_cast<float2*>(dvT) + idx * NRD;
    const float2* dsrc = reinterpret_cast<const float2*>(del_v) + c * NRD * NW + w;
    #pragma unroll
    for (int r = 0; r < NRD; ++r) dt[r] = dsrc[r * NW];
}

struct V6 { float4 m0, m1, m2, m3, d0, d1; };

template <bool TR>
__device__ __forceinline__ V6 load_v(const float* __restrict__ mvT, const float* __restrict__ dvT,
                                     const float* __restrict__ mod_v, const float* __restrict__ del_v,
                                     int c, int w)
{
    V6 r;
    if (TR) {
        const float4* mp = reinterpret_cast<const float4*>(mvT) + (c * NW + w) * 4;
        r.m0 = mp[0]; r.m1 = mp[1]; r.m2 = mp[2]; r.m3 = mp[3];
        const float4* dp = reinterpret_cast<const float4*>(dvT) + (c * NW + w) * 2;
        r.d0 = dp[0]; r.d1 = dp[1];
    } else {
        const float2* m = reinterpret_cast<const float2*>(mod_v) + c * NRM * NW + w;
        float2 a0 = m[0], a1 = m[NW], a2 = m[2*NW], a3 = m[3*NW];
        float2 a4 = m[4*NW], a5 = m[5*NW], a6 = m[6*NW], a7 = m[7*NW];
        r.m0 = make_float4(a0.x, a0.y, a1.x, a1.y);
        r.m1 = make_float4(a2.x, a2.y, a3.x, a3.y);
        r.m2 = make_float4(a4.x, a4.y, a5.x, a5.y);
        r.m3 = make_float4(a6.x, a6.y, a7.x, a7.y);
        const float2* d = reinterpret_cast<const float2*>(del_v) + c * NRD * NW + w;
        float2 b0 = d[0], b1 = d[NW], b2 = d[2*NW], b3 = d[3*NW];
        r.d0 = make_float4(b0.x, b0.y, b1.x, b1.y);
        r.d1 = make_float4(b2.x, b2.y, b3.x, b3.y);
    }
    return r;
}

template <bool TR>
__global__ __launch_bounds__(256)
void fused_kernel(const float* __restrict__ base, const float* __restrict__ mod_u,
                  const float* __restrict__ mod_v, const float* __restrict__ del_u,
                  const float* __restrict__ del_v, const float* __restrict__ exp_base,
                  const float* __restrict__ exp_mod, const float* __restrict__ exp_del,
                  const float* __restrict__ bias_, const float* __restrict__ scale_,
                  const float* __restrict__ coef, float* __restrict__ out,
                  const float* __restrict__ mvT, const float* __restrict__ dvT)
{
    // wave-private staging: [2 rows][4 waves][64 pixels][16 c] u32 (f16 r,i packed)
    __shared__ uint32_t lds[8192];                 // 32 KB
    __shared__ float4 uA4[NC][2][4];               // mod_u rows, 2 KB
    __shared__ float4 uD4[NC][2][2];               // del_u rows, 1 KB

    const int tid    = threadIdx.x;
    const int lane   = tid & 63;
    const int wv     = tid >> 6;
    const int wchunk = (int)(blockIdx.x & 3);
    const int hp     = (int)(blockIdx.x >> 2);
    const int w      = (wchunk << 8) | tid;
    const int h0     = hp * 2;
    const int wbase  = (wchunk << 8) | (wv << 6);

    // ---------- cooperative preload of block-uniform u-tables ----------
    {
        float* uAf = reinterpret_cast<float*>(uA4);   // [c][rr][16 floats]
        float* uDf = reinterpret_cast<float*>(uD4);   // [c][rr][8 floats]
        int i = tid;                                  // 512 floats for uA
        {
            const int c = i >> 5, rr = (i >> 4) & 1, e = i & 15;
            uAf[i] = mod_u[((c * NH) + (h0 + rr)) * (NRM * 2) + e];
        }
        i = tid + 256;
        {
            const int c = i >> 5, rr = (i >> 4) & 1, e = i & 15;
            uAf[i] = mod_u[((c * NH) + (h0 + rr)) * (NRM * 2) + e];
        }
        if (tid < 256) {                              // 256 floats for uD
            const int c = tid >> 4, rr = (tid >> 3) & 1, e = tid & 7;
            uDf[tid] = del_u[((c * NH) + (h0 + rr)) * (NRD * 2) + e];
        }
    }
    __syncthreads();

    // ---------- per-thread A-fragments + bias-const accumulator seed ----------
    const int vv = lane & 15;          // M index (v)
    const int c0 = (lane >> 4) << 2;   // K block (c)

    const float4 cfa = *reinterpret_cast<const float4*>(coef   + (vv * NC + c0) * 2);
    const float4 cfb = *reinterpret_cast<const float4*>(coef   + (vv * NC + c0) * 2 + 4);
    const float4 sca = *reinterpret_cast<const float4*>(scale_ + c0 * 2);
    const float4 scb = *reinterpret_cast<const float4*>(scale_ + c0 * 2 + 4);
    const float4 bia = *reinterpret_cast<const float4*>(bias_  + c0 * 2);
    const float4 bib = *reinterpret_cast<const float4*>(bias_  + c0 * 2 + 4);

    float c2r0 = cfa.x*sca.x - cfa.y*sca.y, c2i0 = cfa.x*sca.y + cfa.y*sca.x;
    float c2r1 = cfa.z*sca.z - cfa.w*sca.w, c2i1 = cfa.z*sca.w + cfa.w*sca.z;
    float c2r2 = cfb.x*scb.x - cfb.y*scb.y, c2i2 = cfb.x*scb.y + cfb.y*scb.x;
    float c2r3 = cfb.z*scb.z - cfb.w*scb.w, c2i3 = cfb.z*scb.w + cfb.w*scb.z;

    const f16x4 Ar = mk4(pkh(c2r0, c2r1), pkh(c2r2, c2r3));
    const f16x4 Ai = mk4(pkh(c2i0, c2i1), pkh(c2i2, c2i3));
    const f16x4 An = mk4(pkh(-c2i0, -c2i1), pkh(-c2i2, -c2i3));

    const f16x4 Kr = mk4(pkh(cfa.x, cfa.z), pkh(cfb.x, cfb.z));
    const f16x4 Ki = mk4(pkh(cfa.y, cfa.w), pkh(cfb.y, cfb.w));
    const f16x4 Kn = mk4(pkh(-cfa.y, -cfa.w), pkh(-cfb.y, -cfb.w));

    const f16x4 Bbr = mk4(pkh(bia.x, bia.z), pkh(bib.x, bib.z));
    const f16x4 Bbi = mk4(pkh(bia.y, bia.w), pkh(bib.y, bib.w));

    const f32x4 zero4 = {0.f, 0.f, 0.f, 0.f};
    const f32x4 cr4 = MFMA16(Kr, Bbr, MFMA16(Kn, Bbi, zero4));  // Re(sum coef*bias)
    const f32x4 ci4 = MFMA16(Ki, Bbr, MFMA16(Kr, Bbi, zero4));  // Im(sum coef*bias)

    // ---------- base power, per row ----------
    const float ebr = exp_base[0], ebi = exp_base[1];
    const float2 b0 = reinterpret_cast<const float2*>(base)[(h0    ) * NW + w];
    const float2 b1 = reinterpret_cast<const float2*>(base)[(h0 + 1) * NW + w];
    const cfloat pb0 = cpow_(b0.x, b0.y, ebr, ebi);
    const cfloat pb1 = cpow_(b1.x, b1.y, ebr, ebi);

    uint32_t* wlds0 = lds + (wv << 10);          // row 0 region (4 KB/wave)
    uint32_t* wlds1 = lds + 4096 + (wv << 10);   // row 1 region
    const int swz_w = (lane >> 1) & 3;

    // ---------- main loop over c with register prefetch ----------
    V6 cur = load_v<TR>(mvT, dvT, mod_v, del_v, 0, w);

    #pragma unroll 1
    for (int a = 0; a < 4; ++a) {
        uint32_t p0[4], p1[4];
        #pragma unroll
        for (int j = 0; j < 4; ++j) {
            const int c = (a << 2) | j;
            V6 nxt = load_v<TR>(mvT, dvT, mod_v, del_v, (c + 1) & 15, w);

            const float emr = exp_mod[2*c], emi = exp_mod[2*c+1];
            const float edr = exp_del[2*c], edi = exp_del[2*c+1];

            #pragma unroll
            for (int rr = 0; rr < 2; ++rr) {
                const float4 ua  = uA4[c][rr][0];
                const float4 ub  = uA4[c][rr][1];
                const float4 uc_ = uA4[c][rr][2];
                const float4 ud  = uA4[c][rr][3];
                const float4 da  = uD4[c][rr][0];
                const float4 db  = uD4[c][rr][1];

                float tr_ = 0.f, ti_ = 0.f;
                CMAC(ua.x,  ua.y,  cur.m0.x, cur.m0.y);
                CMAC(ua.z,  ua.w,  cur.m0.z, cur.m0.w);
                CMAC(ub.x,  ub.y,  cur.m1.x, cur.m1.y);
                CMAC(ub.z,  ub.w,  cur.m1.z, cur.m1.w);
                CMAC(uc_.x, uc_.y, cur.m2.x, cur.m2.y);
                CMAC(uc_.z, uc_.w, cur.m2.z, cur.m2.w);
                CMAC(ud.x,  ud.y,  cur.m3.x, cur.m3.y);
                CMAC(ud.z,  ud.w,  cur.m3.z, cur.m3.w);
                const float mr = tr_, mi_ = ti_;

                tr_ = 0.f; ti_ = 0.f;
                CMAC(da.x, da.y, cur.d0.x, cur.d0.y);
                CMAC(da.z, da.w, cur.d0.z, cur.d0.w);
                CMAC(db.x, db.y, cur.d1.x, cur.d1.y);
                CMAC(db.z, db.w, cur.d1.z, cur.d1.w);
                const float dr = tr_, di = ti_;

                const cfloat pm = cpow_(mr, mi_, emr, emi);
                const cfloat pd = cpow_(dr, di,  edr, edi);

                const float pbr = rr ? pb1.x : pb0.x;
                const float pbi = rr ? pb1.y : pb0.y;
                const float Pr = fmaf(pbr, pm.x, fmaf(-pbi, pm.y, pd.x));
                const float Pi = fmaf(pbr, pm.y, fmaf( pbi, pm.x, pd.y));
                const uint32_t pk = pkh(Pr, Pi);
                if (rr == 0) p0[j] = pk; else p1[j] = pk;
            }
            cur = nxt;
        }
        const int s = (a ^ swz_w) << 2;   // swizzled 16B slot
        *reinterpret_cast<uint4*>(wlds0 + (lane << 4) + s) = make_uint4(p0[0], p0[1], p0[2], p0[3]);
        *reinterpret_cast<uint4*>(wlds1 + (lane << 4) + s) = make_uint4(p1[0], p1[1], p1[2], p1[3]);
    }

    // ---------- MFMA einsum: out[v,pix] = sum_c coef2[v,c] * P[c,pix] + const ----------
    const int ar  = lane >> 4;
    const int col = lane & 15;
    float2* outp = reinterpret_cast<float2*>(out);

    #pragma unroll
    for (int rr = 0; rr < 2; ++rr) {
        const uint32_t* reg = rr ? wlds1 : wlds0;
        const int h = h0 + rr;
        #pragma unroll
        for (int g = 0; g < 4; ++g) {
            const int p = (g << 4) | col;
            const int s = (ar ^ ((p >> 1) & 3)) << 2;
            const uint4 q = *reinterpret_cast<const uint4*>(reg + (p << 4) + s);
            const f16x4 Brf = mk4(__builtin_amdgcn_perm(q.y, q.x, 0x05040100u),
                                  __builtin_amdgcn_perm(q.w, q.z, 0x05040100u));
            const f16x4 Bif = mk4(__builtin_amdgcn_perm(q.y, q.x, 0x07060302u),
                                  __builtin_amdgcn_perm(q.w, q.z, 0x07060302u));
            const f32x4 Dr = MFMA16(Ar, Brf, MFMA16(An, Bif, cr4));
            const f32x4 Di = MFMA16(Ai, Brf, MFMA16(Ar, Bif, ci4));
            const int wg = wbase + (g << 4) + col;
            const int base_idx = h * NW + wg;
            #pragma unroll
            for (int j = 0; j < 4; ++j) {
                const int v = (ar << 2) + j;
                outp[v * (NH * NW) + base_idx] = make_float2(Dr[j], Di[j]);
            }
        }
    }
}

extern "C" void kernel_launch(void* const* d_in, const int* in_sizes, int n_in,
                              void* d_out, int out_size, void* d_ws, size_t ws_size,
                              hipStream_t stream) {
    const float* base     = (const float*)d_in[0];
    const float* mod_u    = (const float*)d_in[1];
    const float* mod_v    = (const float*)d_in[2];
    const float* del_u    = (const float*)d_in[3];
    const float* del_v    = (const float*)d_in[4];
    const float* exp_base = (const float*)d_in[5];
    const float* exp_mod  = (const float*)d_in[6];
    const float* exp_del  = (const float*)d_in[7];
    const float* bias_    = (const float*)d_in[8];
    const float* scale_   = (const float*)d_in[9];
    const float* coef     = (const float*)d_in[10];
    float* outp = (float*)d_out;

    const int blocks = (NH / 2) * (NW / 256);   // 2048
    const size_t mvT_floats = (size_t)NC * NW * NRM * 2;   // 262144 (1 MB)
    const size_t dvT_floats = (size_t)NC * NW * NRD * 2;   // 131072 (0.5 MB)
    const size_t need = (mvT_floats + dvT_floats) * sizeof(float);

    if (ws_size >= need) {
        float* mvT = (float*)d_ws;
        float* dvT = mvT + mvT_floats;
        transpose_v<<<(NC * NW) / 256, 256, 0, stream>>>(mod_v, del_v, mvT, dvT);
        fused_kernel<true><<<blocks, 256, 0, stream>>>(base, mod_u, mod_v, del_u, del_v,
                                                       exp_base, exp_mod, exp_del,
                                                       bias_, scale_, coef, outp, mvT, dvT);
    } else {
        fused_kernel<false><<<blocks, 256, 0, stream>>>(base, mod_u, mod_v, del_u, del_v,
                                                        exp_base, exp_mod, exp_del,
                                                        bias_, scale_, coef, outp,
                                                        (const float*)nullptr, (const float*)nullptr);
    }
}